// Round 6
// baseline (566.831 us; speedup 1.0000x reference)
//
#include <hip/hip_runtime.h>
#include <hip/hip_bf16.h>

using bf16 = __hip_bfloat16;
typedef __attribute__((ext_vector_type(8))) short short8;
typedef __attribute__((ext_vector_type(4))) short short4v;
typedef __attribute__((ext_vector_type(4))) float float4v;

__device__ __forceinline__ float b2f(bf16 x){ return __bfloat162float(x); }
__device__ __forceinline__ bf16  f2b(float x){ return __float2bfloat16(x); }
__device__ __forceinline__ bf16  tob(float x){ return f2b(x); }
__device__ __forceinline__ bf16  tob(bf16 x){ return x; }
__device__ __forceinline__ float frcp(float x){ return __builtin_amdgcn_rcpf(x); }

#define EPSV 1e-5f

// ------------------------------------------------------------------
// pos prep: posf[r] = {x,y,z,|p|^2} fp32
// ------------------------------------------------------------------
__global__ __launch_bounds__(256) void pos_kernel(const float* __restrict__ pos,
                                                  float* __restrict__ posf, int rows){
  int r = blockIdx.x*256 + threadIdx.x;
  if (r >= rows) return;
  float x = pos[3*r], y = pos[3*r+1], z = pos[3*r+2];
  posf[4*r] = x; posf[4*r+1] = y; posf[4*r+2] = z; posf[4*r+3] = x*x + y*y + z*z;
}

// ------------------------------------------------------------------
// all 10 weight transposes (fp32 -> bf16) in ONE launch
// ------------------------------------------------------------------
struct WTDesc { const float* src; bf16* dst; int rows, cols; };
struct WTPack { WTDesc d[10]; };

__global__ __launch_bounds__(256) void wtrans_kernel(WTPack p){
  WTDesc w = p.d[blockIdx.z];
  long r0 = (long)blockIdx.y*32, c0 = (long)blockIdx.x*32;
  if (r0 >= w.rows || c0 >= w.cols) return;
  __shared__ bf16 tile[32][33];
  int tx = threadIdx.x & 31, ty = threadIdx.x >> 5;
#pragma unroll
  for (int i = ty; i < 32; i += 8) tile[i][tx] = f2b(w.src[(r0+i)*w.cols + c0 + tx]);
  __syncthreads();
#pragma unroll
  for (int i = ty; i < 32; i += 8) w.dst[(c0+i)*w.rows + r0 + tx] = tile[tx][i];
}

// ------------------------------------------------------------------
// batched 32x32-tiled transpose (+ cast to bf16)
// ------------------------------------------------------------------
template<typename TI>
__global__ __launch_bounds__(256) void transpose_kernel(
    const TI* __restrict__ in, long ldin, long is1, long is2,
    bf16* __restrict__ out, long ldout, long os1, long os2, int Z2)
{
  int z = blockIdx.z, z1 = z / Z2, z2 = z - z1*Z2;
  in  += (long)z1*is1 + (long)z2*is2;
  out += (long)z1*os1 + (long)z2*os2;
  __shared__ bf16 tile[32][33];
  int tx = threadIdx.x & 31, ty = threadIdx.x >> 5;
  long r0 = (long)blockIdx.y*32, c0 = (long)blockIdx.x*32;
#pragma unroll
  for (int i = ty; i < 32; i += 8) tile[i][tx] = tob(in[(r0+i)*ldin + c0 + tx]);
  __syncthreads();
#pragma unroll
  for (int i = ty; i < 32; i += 8) out[(c0+i)*ldout + r0 + tx] = tile[tx][i];
}

// ------------------------------------------------------------------
// bias concat for fused QKV
// ------------------------------------------------------------------
__global__ __launch_bounds__(256) void bcat_kernel(const float* __restrict__ bq,
                                                   const float* __restrict__ bk,
                                                   const float* __restrict__ bv,
                                                   float* __restrict__ bqkv){
  int j = blockIdx.x*256 + threadIdx.x;
  if (j >= 768) return;
  bqkv[j] = (j < 256) ? bq[j] : (j < 512) ? bk[j-256] : bv[j-512];
}

// ------------------------------------------------------------------
// zero fp32 accumulators
// ------------------------------------------------------------------
__global__ __launch_bounds__(256) void zero_kernel(float4v* __restrict__ p, long n4){
  long i = (long)blockIdx.x*256 + threadIdx.x;
  if (i < n4) p[i] = (float4v){0.f,0.f,0.f,0.f};
}

// ------------------------------------------------------------------
// fp32 -> bf16 convert
// ------------------------------------------------------------------
__global__ __launch_bounds__(256) void cvt_kernel(const float4v* __restrict__ in,
                                                  short4v* __restrict__ out, long n4){
  long i = (long)blockIdx.x*256 + threadIdx.x;
  if (i >= n4) return;
  float4v x = in[i];
  short4v o;
#pragma unroll
  for (int k=0;k<4;k++){ bf16 h = f2b(x[k]); o[k] = *(short*)&h; }
  out[i] = o;
}

// ------------------------------------------------------------------
// LayerNorm over S=256 per row, one-pass sum/sumsq (fp32 in -> bf16 out)
// ------------------------------------------------------------------
__global__ __launch_bounds__(256) void ln_kernel(const float* __restrict__ x,
                                                 const float* __restrict__ g,
                                                 const float* __restrict__ be,
                                                 bf16* __restrict__ out){
  const long row = blockIdx.x;
  const int t = threadIdx.x;
  __shared__ float r1[256], r2[256];
  float v = x[(row<<8) + t];
  r1[t] = v; r2[t] = v*v; __syncthreads();
  for (int s=128;s>0;s>>=1){
    if (t<s){ r1[t] += r1[t+s]; r2[t] += r2[t+s]; }
    __syncthreads();
  }
  const float mu = r1[0] * (1.f/256.f);
  const float var = r2[0] * (1.f/256.f) - mu*mu;
  const float rstd = rsqrtf(fmaxf(var, 0.f) + EPSV);
  out[(row<<8)+t] = f2b((v-mu)*rstd*g[t] + be[t]);
}

// ------------------------------------------------------------------
// eq-norm 1: v (b,n,c,x) fp32 -> vnX[(b,n,x), c] bf16
// ------------------------------------------------------------------
__global__ __launch_bounds__(192) void vnorm1_kernel(const float* __restrict__ vin,
                                                     const float* __restrict__ vs1,
                                                     bf16* __restrict__ vnX){
  const long row = blockIdx.x;
  const int t = threadIdx.x;
  __shared__ float vv[192], nrm[64];
  __shared__ float smean;
  vv[t] = vin[row*192 + t];
  __syncthreads();
  if (t < 64){
    float a = vv[3*t], b = vv[3*t+1], c = vv[3*t+2];
    nrm[t] = sqrtf(a*a + b*b + c*c);
  }
  __syncthreads();
  if (t == 0){ float s = 0.f; for (int i=0;i<64;i++) s += nrm[i]; smean = s*(1.f/64.f); }
  __syncthreads();
  const int c = t/3, x = t - 3*c;
  const float val = vv[t] / (nrm[c] + EPSV) * smean * vs1[c];
  vnX[row*192 + x*64 + c] = f2b(val);
}

// ------------------------------------------------------------------
// eq-norm 2: v2X[(b,n), x*64+c] fp32 -> vn2X same layout bf16
// ------------------------------------------------------------------
__global__ __launch_bounds__(192) void vnorm2_kernel(const float* __restrict__ v2X,
                                                     const float* __restrict__ vs2,
                                                     bf16* __restrict__ vn2X){
  const long row = blockIdx.x;
  const int t = threadIdx.x;
  __shared__ float vv[192], nrm[64];
  __shared__ float smean;
  vv[t] = v2X[row*192 + t];
  __syncthreads();
  if (t < 64){
    float a = vv[t], b = vv[t+64], c = vv[t+128];
    nrm[t] = sqrtf(a*a + b*b + c*c);
  }
  __syncthreads();
  if (t == 0){ float s = 0.f; for (int i=0;i<64;i++) s += nrm[i]; smean = s*(1.f/64.f); }
  __syncthreads();
  const int c = t & 63;
  vn2X[row*192 + t] = f2b(vv[t] / (nrm[c] + EPSV) * smean * vs2[c]);
}

// ------------------------------------------------------------------
// fused bias+softmax (all 4 heads) + head-mean
// ------------------------------------------------------------------
__device__ __forceinline__ float block_red(float x, int op, volatile float* wred,
                                           int lane, int wv){
#pragma unroll
  for (int off=32; off; off>>=1){
    float o = __shfl_xor(x, off, 64);
    x = op ? (x+o) : fmaxf(x,o);
  }
  if (lane==0) wred[wv] = x;
  __syncthreads();
  float r = op ? (wred[0]+wred[1]+wred[2]+wred[3])
               : fmaxf(fmaxf(wred[0],wred[1]), fmaxf(wred[2],wred[3]));
  __syncthreads();
  return r;
}

__global__ __launch_bounds__(256) void softmax_am_kernel(
    bf16* __restrict__ P, const float* __restrict__ posf,
    const float* __restrict__ w_dist, const float* __restrict__ b_dist,
    bf16* __restrict__ AM)
{
  const int bn = blockIdx.x;
  const int b = bn >> 11, n = bn & 2047;
  const int t = threadIdx.x;
  const int lane = t & 63, wv = t >> 6;
  __shared__ float wred[4];
  const float* pb = posf + (long)b*8192;
  const float4v pn = *(const float4v*)(pb + 4*n);
  float dist[8], am[8];
#pragma unroll
  for (int i=0;i<8;i++){
    const int m = t + (i<<8);
    const float4v pm = *(const float4v*)(pb + 4*m);
    float d2 = pn[3] + pm[3] - 2.f*(pn[0]*pm[0] + pn[1]*pm[1] + pn[2]*pm[2]);
    dist[i] = sqrtf(fmaxf(d2, 1e-12f));
    am[i] = 0.f;
  }
#pragma unroll
  for (int h=0;h<4;h++){
    bf16* row = P + ((((long)(b*4+h))*2048 + n) << 11);
    const float wh = w_dist[h], bh = b_dist[h];
    float q8[8], mx = -1e30f;
#pragma unroll
    for (int i=0;i<8;i++){
      q8[i] = b2f(row[t + (i<<8)]) * 0.125f;
      mx = fmaxf(mx, q8[i]);
    }
    mx = block_red(mx, 0, wred, lane, wv);
    float p[8], sum = 0.f;
#pragma unroll
    for (int i=0;i<8;i++){
      float sig = frcp(1.f + __expf(dist[i]*wh + bh));
      p[i] = __expf(q8[i] - mx) * sig;
      sum += p[i];
    }
    sum = block_red(sum, 1, wred, lane, wv);
    const float inv = frcp(sum);
#pragma unroll
    for (int i=0;i<8;i++){
      float pv = p[i]*inv;
      row[t + (i<<8)] = f2b(pv);
      am[i] += pv;
    }
  }
  bf16* amrow = AM + ((long)bn << 11);
#pragma unroll
  for (int i=0;i<8;i++) amrow[t + (i<<8)] = f2b(am[i]*0.25f);
}

// ------------------------------------------------------------------
// MFMA GEMM. 256 threads = 4 independent waves; wave w handles logical
// tile idx = blockIdx.y*4+w, decomposed as ytile = idx%LY, z = idx/LY.
// z then decomposes into K-split slice ks = z%KS and batch zz = z/KS
// (zz -> z1,z2 via Z2). K-loop unrolled x2 (K must be a multiple of 64)
// for 2x memory-level parallelism.
// OUTM: 0 = bf16 store, 1 = fp32 store, 2 = fp32 unsafeAtomicAdd.
// ACT: 1 = exact-erf GELU. RXIL/CXIL: x-interleaved resid/store addressing.
// ------------------------------------------------------------------
template<int MT, int NT, int ACT, int OUTM, int RXIL, int CXIL>
__global__ __launch_bounds__(256) void gemm_kernel(
    const bf16* __restrict__ A, long lda, long As1, long As2,
    const bf16* __restrict__ BT, long ldb, long Bs1, long Bs2,
    const float* __restrict__ bias,
    const float* __restrict__ resid, long ldr, long Rs1, long Rs2,
    void* __restrict__ Cv, long ldc, long Cs1, long Cs2,
    int LY, int K, int Z2, int KS)
{
  const int wvid = threadIdx.x >> 6;
  const int lane = threadIdx.x & 63;
  const int idx = blockIdx.y*4 + wvid;
  const int ytile = idx % LY;
  const int z = idx / LY;
  int zz = z / KS, ks = z - zz*KS;
  int z1 = zz / Z2, z2 = zz - z1*Z2;
  A  += (long)z1*As1 + (long)z2*As2 + (long)ks*K;
  BT += (long)z1*Bs1 + (long)z2*Bs2 + (long)ks*K;
  if (resid) resid += (long)z1*Rs1 + (long)z2*Rs2;
  const long cbase = (long)z1*Cs1 + (long)z2*Cs2;

  const int col = lane & 15, quad = lane >> 4;
  const long rowA0 = (long)ytile*(16*MT);
  const long colB0 = (long)blockIdx.x*(16*NT);

  float4v acc[MT][NT];
#pragma unroll
  for (int m=0;m<MT;m++)
#pragma unroll
    for (int n=0;n<NT;n++) acc[m][n] = (float4v){0.f,0.f,0.f,0.f};

  const bf16* ap[MT];
  const bf16* bp[NT];
#pragma unroll
  for (int m=0;m<MT;m++) ap[m] = A + (rowA0 + m*16 + col)*lda + quad*8;
#pragma unroll
  for (int n=0;n<NT;n++) bp[n] = BT + (colB0 + n*16 + col)*ldb + quad*8;

  for (int k0 = 0; k0 < K; k0 += 64){
    short8 a0[MT], a1[MT], b0[NT], b1[NT];
#pragma unroll
    for (int m=0;m<MT;m++){
      a0[m] = *(const short8*)ap[m];
      a1[m] = *(const short8*)(ap[m] + 32);
      ap[m] += 64;
    }
#pragma unroll
    for (int n=0;n<NT;n++){
      b0[n] = *(const short8*)bp[n];
      b1[n] = *(const short8*)(bp[n] + 32);
      bp[n] += 64;
    }
#pragma unroll
    for (int m=0;m<MT;m++)
#pragma unroll
      for (int n=0;n<NT;n++)
        acc[m][n] = __builtin_amdgcn_mfma_f32_16x16x32_bf16(a0[m], b0[n], acc[m][n], 0, 0, 0);
#pragma unroll
    for (int m=0;m<MT;m++)
#pragma unroll
      for (int n=0;n<NT;n++)
        acc[m][n] = __builtin_amdgcn_mfma_f32_16x16x32_bf16(a1[m], b1[n], acc[m][n], 0, 0, 0);
  }

#pragma unroll
  for (int m=0;m<MT;m++){
    const long ri = rowA0 + m*16 + quad*4;
#pragma unroll
    for (int n=0;n<NT;n++){
      const long cj = colB0 + n*16 + col;
      const float bbias = bias ? bias[cj] : 0.f;
#pragma unroll
      for (int r=0;r<4;r++){
        const long ci = ri + r;
        float val = acc[m][n][r] + bbias;
        if (ACT == 1) val = 0.5f*val*(1.f + erff(val*0.70710678118654752f));
        if (resid){
          const long raddr = RXIL ? ((ci/3)*192 + cj*3 + (ci%3)) : (ci*ldr + cj);
          val += resid[raddr];
        }
        const long caddr = CXIL ? (cbase + (ci/3)*192 + cj*3 + (ci%3))
                                : (cbase + ci*ldc + cj);
        if (OUTM == 0)      ((bf16*)Cv)[caddr] = f2b(val);
        else if (OUTM == 1) ((float*)Cv)[caddr] = val;
        else                unsafeAtomicAdd(&((float*)Cv)[caddr], val);
      }
    }
  }
}

// ------------------------------------------------------------------
extern "C" void kernel_launch(void* const* d_in, const int* in_sizes, int n_in,
                              void* d_out, int out_size, void* d_ws, size_t ws_size,
                              hipStream_t stream)
{
  const float* s    = (const float*)d_in[0];
  const float* v    = (const float*)d_in[1];
  const float* pos  = (const float*)d_in[2];
  const float* Wq   = (const float*)d_in[3];
  const float* bq   = (const float*)d_in[4];
  const float* Wk   = (const float*)d_in[5];
  const float* bk   = (const float*)d_in[6];
  const float* Wv   = (const float*)d_in[7];
  const float* bv   = (const float*)d_in[8];
  const float* Wo   = (const float*)d_in[9];
  const float* bo   = (const float*)d_in[10];
  const float* w_d  = (const float*)d_in[11];
  const float* b_d  = (const float*)d_in[12];
  const float* Wvv  = (const float*)d_in[13];
  const float* Wvo  = (const float*)d_in[14];
  const float* g1   = (const float*)d_in[15];
  const float* be1  = (const float*)d_in[16];
  const float* vs1  = (const float*)d_in[17];
  const float* g2   = (const float*)d_in[18];
  const float* be2  = (const float*)d_in[19];
  const float* vs2  = (const float*)d_in[20];
  const float* Wf1  = (const float*)d_in[21];
  const float* bf1  = (const float*)d_in[22];
  const float* Wf2  = (const float*)d_in[23];
  const float* bf2  = (const float*)d_in[24];
  const float* Wfv1 = (const float*)d_in[25];
  const float* Wfv2 = (const float*)d_in[26];

  float* outS = (float*)d_out;
  float* outV = outS + (size_t)4*2048*256;

  char* w = (char*)d_ws;
  size_t o = 0;
  auto alloc = [&](size_t bytes)->char* {
    char* p = w + o;
    o = (o + bytes + 255) & ~(size_t)255;
    return p;
  };
  float* posf  = (float*)alloc(131072);
  bf16* WqkvT = (bf16*)alloc(393216);       // 768 x 256
  bf16* WoT   = (bf16*)alloc(131072);
  bf16* Wf1T  = (bf16*)alloc(524288);
  bf16* Wf2T  = (bf16*)alloc(524288);
  bf16* WvvT  = (bf16*)alloc(8192);
  bf16* WvoT  = (bf16*)alloc(8192);
  bf16* Wfv1T = (bf16*)alloc(32768);
  bf16* Wfv2T = (bf16*)alloc(32768);
  float* bqkv = (float*)alloc(3072);
  bf16* sn    = (bf16*)alloc(4194304);      // reused for sn2
  bf16* qkv   = (bf16*)alloc(12582912);     // later alias: hv
  bf16* vsT   = (bf16*)alloc(4194304);
  bf16* sA    = (bf16*)alloc(4194304);
  float* s2   = (float*)alloc(8388608);
  bf16* vnX   = (bf16*)alloc(3145728);      // later alias: vn2X
  bf16* vmixX = (bf16*)alloc(3145728);      // later alias: tvXb
  bf16* vmixXT= (bf16*)alloc(3145728);
  float* v2X  = (float*)alloc(6291456);
  bf16* P     = (bf16*)alloc(134217728);    // later alias: h1
  bf16* AM    = (bf16*)alloc(33554432);
  char* accbuf= alloc(14680064);            // sAf + tvX
  float* sAf  = (float*)accbuf;
  float* tvX  = (float*)(accbuf + 8388608);
  bf16* vn2X  = vnX;
  bf16* tvXb  = vmixX;
  bf16* hv    = qkv;
  bf16* h1    = P;
  if (o > ws_size) return;

  // --- prep ---
  pos_kernel<<<32, 256, 0, stream>>>(pos, posf, 8192);
  WTPack pk;
  pk.d[0] = {Wq,   WqkvT,          256, 256};
  pk.d[1] = {Wk,   WqkvT + 65536,  256, 256};
  pk.d[2] = {Wv,   WqkvT + 131072, 256, 256};
  pk.d[3] = {Wo,   WoT,            256, 256};
  pk.d[4] = {Wf1,  Wf1T,           256, 1024};
  pk.d[5] = {Wf2,  Wf2T,           1024, 256};
  pk.d[6] = {Wvv,  WvvT,           64, 64};
  pk.d[7] = {Wvo,  WvoT,           64, 64};
  pk.d[8] = {Wfv1, Wfv1T,          64, 256};
  pk.d[9] = {Wfv2, Wfv2T,          256, 64};
  wtrans_kernel<<<dim3(32,32,10), 256, 0, stream>>>(pk);
  bcat_kernel<<<3, 256, 0, stream>>>(bq, bk, bv, bqkv);

  // --- norm1 (scalar + vector) ---
  ln_kernel<<<8192, 256, 0, stream>>>(s, g1, be1, sn);
  vnorm1_kernel<<<8192, 192, 0, stream>>>(v, vs1, vnX);

  // --- vmixX = vnX @ WvvT: (24576 x 64), K=64; LY=768 ---
  gemm_kernel<2,4,0,0,0,0><<<dim3(1,192,1), 256, 0, stream>>>(vnX,64,0,0, WvvT,64,0,0,
      nullptr, nullptr,0,0,0, vmixX,64,0,0, 768, 64, 1, 1);
  transpose_kernel<bf16><<<dim3(6,64,4), 256, 0, stream>>>(vmixX, 192, 393216,0,
      vmixXT, 2048, 393216,0, 1);

  // --- fused QKV projection: M=8192, N=768, K=256; LY=256 ---
  gemm_kernel<2,4,0,0,0,0><<<dim3(12,64,1), 256, 0, stream>>>(sn,256,0,0, WqkvT,256,0,0,
      bqkv, nullptr,0,0,0, qkv,768,0,0, 256, 256, 1, 1);
  transpose_kernel<bf16><<<dim3(2,64,16), 256, 0, stream>>>(qkv+512, 768, 1572864,64,
      vsT, 2048, 524288,131072, 4);

  // --- logits: per (b,h) 2048x2048, K=64; LY=64, z=16 -> grid.y=256 ---
  gemm_kernel<2,4,0,0,0,0><<<dim3(32,256,1), 256, 0, stream>>>(qkv,768,1572864,64,
      qkv+256,768,1572864,64, nullptr, nullptr,0,0,0, P,2048,16777216,4194304, 64, 64, 4, 1);

  // --- fused dist-bias + softmax + head-mean ---
  softmax_am_kernel<<<8192, 256, 0, stream>>>(P, posf, w_d, b_d, AM);

  // --- zero fp32 accumulators: 14680064 B = 917504 float4 ---
  zero_kernel<<<3584, 256, 0, stream>>>((float4v*)accbuf, 917504);

  // --- PV: per (b,h) 2048x64, K=2048, Ksplit=4; LY=128, z=64 -> grid.y=2048 ---
  gemm_kernel<1,4,0,2,0,0><<<dim3(1,2048,1), 256, 0, stream>>>(P,2048,16777216,4194304,
      vsT,2048,524288,131072, nullptr, nullptr,0,0,0, sAf,256,524288,64, 128, 512, 4, 4);

  // --- v_attn: per b, AM @ vmixXT, K=2048, Ksplit=4; LY=64, z=16 -> grid.y=256 ---
  gemm_kernel<2,4,0,2,0,0><<<dim3(3,256,1), 256, 0, stream>>>(AM,2048,4194304,0,
      vmixXT,2048,393216,0, nullptr, nullptr,0,0,0, tvX,192,393216,0, 64, 512, 1, 4);

  cvt_kernel<<<2048, 256, 0, stream>>>((const float4v*)sAf, (short4v*)sA, 524288);
  cvt_kernel<<<1536, 256, 0, stream>>>((const float4v*)tvX, (short4v*)tvXb, 393216);

  // --- output projection + residual: s2 = s + sA@Wo + bo (fp32); LY=256 ---
  gemm_kernel<2,4,0,1,0,0><<<dim3(4,64,1), 256, 0, stream>>>(sA,256,0,0, WoT,256,0,0,
      bo, s,256,0,0, s2,256,0,0, 256, 256, 1, 1);

  // --- v2X = v (interleaved resid) + tvXb @ WvoT; LY=768, K=64 ---
  gemm_kernel<2,4,0,1,1,0><<<dim3(1,192,1), 256, 0, stream>>>(tvXb,64,0,0, WvoT,64,0,0,
      nullptr, v,0,0,0, v2X,64,0,0, 768, 64, 1, 1);

  // --- norm2 + FFN (h1 aliases P) ---
  ln_kernel<<<8192, 256, 0, stream>>>(s2, g2, be2, sn);
  gemm_kernel<2,4,1,0,0,0><<<dim3(16,64,1), 256, 0, stream>>>(sn,256,0,0, Wf1T,256,0,0,
      bf1, nullptr,0,0,0, h1,1024,0,0, 256, 256, 1, 1);
  gemm_kernel<2,4,0,1,0,0><<<dim3(4,64,1), 256, 0, stream>>>(h1,1024,0,0, Wf2T,1024,0,0,
      bf2, s2,256,0,0, outS,256,0,0, 256, 1024, 1, 1);

  // --- vector FFN: norm2 -> hid GEMM -> out GEMM (+resid, interleaved store) ---
  vnorm2_kernel<<<8192, 192, 0, stream>>>(v2X, vs2, vn2X);
  gemm_kernel<2,4,0,0,0,0><<<dim3(4,192,1), 256, 0, stream>>>(vn2X,64,0,0, Wfv1T,64,0,0,
      nullptr, nullptr,0,0,0, hv,256,0,0, 768, 64, 1, 1);
  gemm_kernel<2,4,0,1,0,1><<<dim3(1,192,1), 256, 0, stream>>>(hv,256,0,0, Wfv2T,256,0,0,
      nullptr, v2X,64,0,0, outV,0,0,0, 768, 256, 1, 1);
}